// Round 2
// baseline (614.702 us; speedup 1.0000x reference)
//
#include <hip/hip_runtime.h>
#include <hip/hip_bf16.h>
#include <math.h>

#define NEG_SLOPE 0.2f

__device__ __forceinline__ float lrelu(float x){ return x > 0.0f ? x : NEG_SLOPE * x; }

// ---------------- CSR build ----------------
__global__ void hist_kernel(const int* __restrict__ dst, int E, int* __restrict__ deg){
  int i = blockIdx.x * blockDim.x + threadIdx.x;
  if (i < E) atomicAdd(&deg[dst[i]], 1);
}

__global__ void scan1_kernel(const int* __restrict__ deg, int N,
                             int* __restrict__ rowptr, int* __restrict__ bsum){
  __shared__ int sdata[256];
  int t = threadIdx.x;
  int base = blockIdx.x * 1024;
  int v[4];
  int run = 0;
#pragma unroll
  for (int j = 0; j < 4; ++j){
    int idx = base + t*4 + j;
    int d = (idx < N) ? deg[idx] : 0;
    run += d;
    v[j] = run;
  }
  sdata[t] = run;
  __syncthreads();
  for (int off = 1; off < 256; off <<= 1){
    int x = (t >= off) ? sdata[t - off] : 0;
    __syncthreads();
    sdata[t] += x;
    __syncthreads();
  }
  int prev = (t > 0) ? sdata[t-1] : 0;
#pragma unroll
  for (int j = 0; j < 4; ++j){
    int idx = base + t*4 + j;
    if (idx < N) rowptr[idx + 1] = v[j] + prev;
  }
  if (t == 255) bsum[blockIdx.x] = sdata[255];
}

__global__ void scan2_kernel(int* __restrict__ bsum, int nb){
  if (threadIdx.x == 0 && blockIdx.x == 0){
    int run = 0;
    for (int i = 0; i < nb; ++i){ int x = bsum[i]; bsum[i] = run; run += x; }
  }
}

__global__ void scan3_kernel(int* __restrict__ rowptr, const int* __restrict__ bsum, int N){
  int i = blockIdx.x * blockDim.x + threadIdx.x;
  if (i == 0) rowptr[0] = 0;
  if (i < N) rowptr[i + 1] += bsum[i >> 10];
}

__global__ void scatter_kernel(const int* __restrict__ src, const int* __restrict__ dst, int E,
                               const int* __restrict__ rowptr, int* __restrict__ fill,
                               int* __restrict__ csr_src){
  int i = blockIdx.x * blockDim.x + threadIdx.x;
  if (i < E){
    int d = dst[i];
    int pos = rowptr[d] + atomicAdd(&fill[d], 1);
    csr_src[pos] = src[i];
  }
}

// ---------------- f32 GEMM: out[N,128] = A[N,128] @ W[128,128] ----------------
__launch_bounds__(256, 2)
__global__ void gemm128_kernel(const float* __restrict__ A, const float* __restrict__ W,
                               float* __restrict__ out, int N){
  __shared__ float Wl[64][128];
  __shared__ float xT[64][64];
  const int t = threadIdx.x;
  const int rg = t >> 5;        // 0..7 -> rows rg*8 .. rg*8+7
  const int cg = t & 31;        // cols cg*4 .. cg*4+3
  const int rowBase = blockIdx.x * 64;
  float4 acc[8];
#pragma unroll
  for (int i = 0; i < 8; ++i) acc[i] = make_float4(0.f,0.f,0.f,0.f);

  for (int kc = 0; kc < 2; ++kc){
    // load W chunk [64][128]
#pragma unroll
    for (int j = 0; j < 8; ++j){
      int f = j*256 + t;
      int k = f >> 5, c4 = f & 31;
      *(float4*)(&Wl[k][c4*4]) = *(const float4*)(W + (kc*64 + k)*128 + c4*4);
    }
    // load A chunk transposed: xT[k][r] = A[rowBase+r][kc*64+k]
#pragma unroll
    for (int j = 0; j < 4; ++j){
      int f = j*256 + t;
      int r = f >> 4, kq = f & 15;
      int row = rowBase + r;
      float4 a = (row < N) ? *(const float4*)(A + (size_t)row*128 + kc*64 + kq*4)
                           : make_float4(0.f,0.f,0.f,0.f);
      xT[kq*4 + 0][r] = a.x;
      xT[kq*4 + 1][r] = a.y;
      xT[kq*4 + 2][r] = a.z;
      xT[kq*4 + 3][r] = a.w;
    }
    __syncthreads();
#pragma unroll 8
    for (int k = 0; k < 64; ++k){
      float4 w  = *(const float4*)(&Wl[k][cg*4]);
      float4 xa = *(const float4*)(&xT[k][rg*8]);
      float4 xb = *(const float4*)(&xT[k][rg*8 + 4]);
      float xr[8] = {xa.x, xa.y, xa.z, xa.w, xb.x, xb.y, xb.z, xb.w};
#pragma unroll
      for (int i = 0; i < 8; ++i){
        acc[i].x += xr[i]*w.x;
        acc[i].y += xr[i]*w.y;
        acc[i].z += xr[i]*w.z;
        acc[i].w += xr[i]*w.w;
      }
    }
    __syncthreads();
  }
#pragma unroll
  for (int i = 0; i < 8; ++i){
    int row = rowBase + rg*8 + i;
    if (row < N) *(float4*)(out + (size_t)row*128 + cg*4) = acc[i];
  }
}

// ---------------- alpha_s / alpha_d: per-node dot with attention vectors ----------------
template<int H>
__global__ void alpha_kernel(const float* __restrict__ h, const float* __restrict__ a_src,
                             const float* __restrict__ a_dst, float* __restrict__ alpha_s,
                             float* __restrict__ alpha_d, int N){
  int wid = threadIdx.x >> 6, lane = threadIdx.x & 63;
  int n = blockIdx.x * 4 + wid;
  if (n >= N) return;
  float2 hv  = *(const float2*)(h + (size_t)n*128 + lane*2);
  float2 as2 = *(const float2*)(a_src + lane*2);
  float2 ad2 = *(const float2*)(a_dst + lane*2);
  float vs = hv.x*as2.x + hv.y*as2.y;
  float vd = hv.x*ad2.x + hv.y*ad2.y;
  const int L = 64 / H;  // lanes per head
#pragma unroll
  for (int off = 1; off < L; off <<= 1){
    vs += __shfl_xor(vs, off);
    vd += __shfl_xor(vd, off);
  }
  if ((lane % L) == 0){
    int hh = lane / L;
    alpha_s[(size_t)n*H + hh] = vs;
    alpha_d[(size_t)n*H + hh] = vd;
  }
}

// ---------------- per-node softmax-aggregation (one wave per node) ----------------
template<int H, bool ELU_OUT>
__global__ void agg_kernel(const float* __restrict__ h, const float* __restrict__ alpha_s,
                           const float* __restrict__ alpha_d, const int* __restrict__ rowptr,
                           const int* __restrict__ csr_src, const float* __restrict__ bias,
                           float* __restrict__ out, int N){
  int wid = threadIdx.x >> 6, lane = threadIdx.x & 63;
  int n = blockIdx.x * 4 + wid;
  if (n >= N) return;
  int start = rowptr[n], end = rowptr[n + 1];

  // ---- Pass A: per-head max of leaky(alpha_s[src]+alpha_d[n]) over edges + self loop
  const int hA = lane % H;
  float adA = alpha_d[(size_t)n*H + hA];
  float mval = lrelu(alpha_s[(size_t)n*H + hA] + adA);   // self loop
  for (int i = start + lane / H; i < end; i += 64 / H){
    int s = csr_src[i];
    mval = fmaxf(mval, lrelu(alpha_s[(size_t)s*H + hA] + adA));
  }
#pragma unroll
  for (int off = H; off < 64; off <<= 1)
    mval = fmaxf(mval, __shfl_xor(mval, off));

  // ---- Pass B: two edges in parallel (half-wave each), 4 channels per lane
  const int l5 = lane & 31;
  const int ch = l5 * 4;
  const int hm = (l5 * H) >> 5;           // head owning these channels
  float m_m  = __shfl(mval, hm);
  float ad_m = alpha_d[(size_t)n*H + hm];

  float4 acc = make_float4(0.f,0.f,0.f,0.f);
  float ssum = 0.f;
  int T = end - start + 1;                // +1 for the self loop (item j==0)
  for (int j = lane >> 5; j < T; j += 2){
    int s = (j == 0) ? n : csr_src[start + j - 1];
    float e  = lrelu(alpha_s[(size_t)s*H + hm] + ad_m);
    float ex = __expf(e - m_m);
    float4 hv = *(const float4*)(h + (size_t)s*128 + ch);
    acc.x += ex*hv.x; acc.y += ex*hv.y; acc.z += ex*hv.z; acc.w += ex*hv.w;
    ssum += ex;
  }
  acc.x += __shfl_xor(acc.x, 32);
  acc.y += __shfl_xor(acc.y, 32);
  acc.z += __shfl_xor(acc.z, 32);
  acc.w += __shfl_xor(acc.w, 32);
  ssum  += __shfl_xor(ssum, 32);

  if (lane < 32){
    float inv = 1.0f / ssum;
    float4 b4 = *(const float4*)(bias + ch);
    float o[4] = {acc.x*inv + b4.x, acc.y*inv + b4.y, acc.z*inv + b4.z, acc.w*inv + b4.w};
    if (ELU_OUT){
#pragma unroll
      for (int i = 0; i < 4; ++i) o[i] = (o[i] > 0.f) ? o[i] : expm1f(o[i]);
    }
    float4 o4 = make_float4(o[0], o[1], o[2], o[3]);
    *(float4*)(out + (size_t)n*128 + ch) = o4;
  }
}

extern "C" void kernel_launch(void* const* d_in, const int* in_sizes, int n_in,
                              void* d_out, int out_size, void* d_ws, size_t ws_size,
                              hipStream_t stream){
  const float* x      = (const float*)d_in[0];
  const int*   ei     = (const int*)  d_in[1];
  const float* W1     = (const float*)d_in[2];
  const float* a_src1 = (const float*)d_in[3];
  const float* a_dst1 = (const float*)d_in[4];
  const float* b1     = (const float*)d_in[5];
  const float* W2     = (const float*)d_in[6];
  const float* a_src2 = (const float*)d_in[7];
  const float* a_dst2 = (const float*)d_in[8];
  const float* b2     = (const float*)d_in[9];
  float* out = (float*)d_out;

  const int N = in_sizes[0] / 128;
  const int E = in_sizes[1] / 2;
  const int* src = ei;
  const int* dst = ei + E;

  char* ws = (char*)d_ws;
  size_t off = 0;
  auto alloc = [&](size_t bytes) -> void* {
    void* p = ws + off;
    off += (bytes + 255) & ~(size_t)255;
    return p;
  };
  float* h      = (float*)alloc((size_t)N * 128 * 4);
  float* act    = (float*)alloc((size_t)N * 128 * 4);
  float* asb    = (float*)alloc((size_t)N * 8 * 4);
  float* adb    = (float*)alloc((size_t)N * 8 * 4);
  int*   csr    = (int*)  alloc((size_t)E * 4);
  int*   rowptr = (int*)  alloc((size_t)(N + 1) * 4);
  int*   deg    = (int*)  alloc((size_t)N * 4);
  int*   fill   = (int*)  alloc((size_t)N * 4);
  int*   bsum   = (int*)  alloc(4096);

  // zero deg + fill (contiguous region between deg and bsum)
  hipMemsetAsync(deg, 0, (size_t)((char*)bsum - (char*)deg), stream);

  const int nb = (N + 1023) / 1024;
  hist_kernel   <<<(E + 255)/256, 256, 0, stream>>>(dst, E, deg);
  scan1_kernel  <<<nb, 256, 0, stream>>>(deg, N, rowptr, bsum);
  scan2_kernel  <<<1, 64, 0, stream>>>(bsum, nb);
  scan3_kernel  <<<(N + 255)/256, 256, 0, stream>>>(rowptr, bsum, N);
  scatter_kernel<<<(E + 255)/256, 256, 0, stream>>>(src, dst, E, rowptr, fill, csr);

  const int gBlocks  = (N + 63) / 64;
  const int nBlocks4 = (N + 3) / 4;

  // layer 1
  gemm128_kernel<<<gBlocks, 256, 0, stream>>>(x, W1, h, N);
  alpha_kernel<8><<<nBlocks4, 256, 0, stream>>>(h, a_src1, a_dst1, asb, adb, N);
  agg_kernel<8, true><<<nBlocks4, 256, 0, stream>>>(h, asb, adb, rowptr, csr, b1, act, N);

  // layer 2
  gemm128_kernel<<<gBlocks, 256, 0, stream>>>(act, W2, h, N);
  alpha_kernel<1><<<nBlocks4, 256, 0, stream>>>(h, a_src2, a_dst2, asb, adb, N);
  agg_kernel<1, false><<<nBlocks4, 256, 0, stream>>>(h, asb, adb, rowptr, csr, b2, out, N);
}

// Round 3
// 483.746 us; speedup vs baseline: 1.2707x; 1.2707x over previous
//
#include <hip/hip_runtime.h>
#include <hip/hip_bf16.h>
#include <math.h>

#define NEG_SLOPE 0.2f

__device__ __forceinline__ float lrelu(float x){ return x > 0.0f ? x : NEG_SLOPE * x; }

__device__ __forceinline__ float bf2f(unsigned int u16){
  union { unsigned int i; float f; } v; v.i = u16 << 16; return v.f;
}
__device__ __forceinline__ unsigned int f2bf(float f){
  union { float f; unsigned int i; } v; v.f = f;
  unsigned int x = v.i;
  return (x + 0x7fffu + ((x >> 16) & 1u)) >> 16;   // RNE
}

// ---------------- CSR build ----------------
__global__ void hist_kernel(const int* __restrict__ dst, int E, int* __restrict__ deg){
  int i = blockIdx.x * blockDim.x + threadIdx.x;
  if (i < E) atomicAdd(&deg[dst[i]], 1);
}

__global__ void scan1_kernel(const int* __restrict__ deg, int N,
                             int* __restrict__ rowptr, int* __restrict__ bsum){
  __shared__ int sdata[256];
  int t = threadIdx.x;
  int base = blockIdx.x * 1024;
  int v[4];
  int run = 0;
#pragma unroll
  for (int j = 0; j < 4; ++j){
    int idx = base + t*4 + j;
    int d = (idx < N) ? deg[idx] : 0;
    run += d;
    v[j] = run;
  }
  sdata[t] = run;
  __syncthreads();
  for (int off = 1; off < 256; off <<= 1){
    int x = (t >= off) ? sdata[t - off] : 0;
    __syncthreads();
    sdata[t] += x;
    __syncthreads();
  }
  int prev = (t > 0) ? sdata[t-1] : 0;
#pragma unroll
  for (int j = 0; j < 4; ++j){
    int idx = base + t*4 + j;
    if (idx < N) rowptr[idx + 1] = v[j] + prev;
  }
  if (t == 255) bsum[blockIdx.x] = sdata[255];
}

__global__ void scan2_kernel(int* __restrict__ bsum, int nb){
  if (threadIdx.x == 0 && blockIdx.x == 0){
    int run = 0;
    for (int i = 0; i < nb; ++i){ int x = bsum[i]; bsum[i] = run; run += x; }
  }
}

__global__ void scan3_kernel(int* __restrict__ rowptr, const int* __restrict__ bsum, int N){
  int i = blockIdx.x * blockDim.x + threadIdx.x;
  if (i == 0) rowptr[0] = 0;
  if (i < N) rowptr[i + 1] += bsum[i >> 10];
}

__global__ void scatter_kernel(const int* __restrict__ src, const int* __restrict__ dst, int E,
                               const int* __restrict__ rowptr, int* __restrict__ fill,
                               int* __restrict__ csr_src){
  int i = blockIdx.x * blockDim.x + threadIdx.x;
  if (i < E){
    int d = dst[i];
    int pos = rowptr[d] + atomicAdd(&fill[d], 1);
    csr_src[pos] = src[i];
  }
}

// ---------------- f32 GEMM -> bf16 out: out[N,128] = A[N,128] @ W[128,128] ----------------
// 128x128 tile, K-chunk 32, 8x8 accum per thread.
__launch_bounds__(256, 4)
__global__ void gemm128_kernel(const float* __restrict__ A, const float* __restrict__ W,
                               unsigned short* __restrict__ out, int N){
  __shared__ float Wl[32][128];
  __shared__ float xT[32][132];   // padded: bank = (4k + row) % 32
  const int t = threadIdx.x;
  const int r0 = (t >> 4) * 8;          // 8 rows
  const int c0 = (t & 15) * 4;          // cols c0..c0+3 and c0+64..c0+67
  const int rowBase = blockIdx.x * 128;
  float acc[8][8];
#pragma unroll
  for (int i = 0; i < 8; ++i)
#pragma unroll
    for (int j = 0; j < 8; ++j) acc[i][j] = 0.f;

  for (int kc = 0; kc < 4; ++kc){
    // stage W chunk [32][128]
#pragma unroll
    for (int j = 0; j < 4; ++j){
      int f = j*256 + t;
      int k = f >> 5, c4 = f & 31;
      *(float4*)(&Wl[k][c4*4]) = *(const float4*)(W + (kc*32 + k)*128 + c4*4);
    }
    // stage A chunk transposed: xT[k][row]
#pragma unroll
    for (int j = 0; j < 4; ++j){
      int f = j*256 + t;
      int row = f >> 3, kq = f & 7;
      int gr = rowBase + row;
      float4 a = (gr < N) ? *(const float4*)(A + (size_t)gr*128 + kc*32 + kq*4)
                          : make_float4(0.f,0.f,0.f,0.f);
      xT[kq*4 + 0][row] = a.x;
      xT[kq*4 + 1][row] = a.y;
      xT[kq*4 + 2][row] = a.z;
      xT[kq*4 + 3][row] = a.w;
    }
    __syncthreads();
#pragma unroll 4
    for (int k = 0; k < 32; ++k){
      float4 xa = *(const float4*)(&xT[k][r0]);
      float4 xb = *(const float4*)(&xT[k][r0 + 4]);
      float4 wa = *(const float4*)(&Wl[k][c0]);
      float4 wb = *(const float4*)(&Wl[k][c0 + 64]);
      float xr[8] = {xa.x, xa.y, xa.z, xa.w, xb.x, xb.y, xb.z, xb.w};
      float wc[8] = {wa.x, wa.y, wa.z, wa.w, wb.x, wb.y, wb.z, wb.w};
#pragma unroll
      for (int i = 0; i < 8; ++i)
#pragma unroll
        for (int j = 0; j < 8; ++j)
          acc[i][j] += xr[i] * wc[j];
    }
    __syncthreads();
  }
  // epilogue: bf16 store (RNE)
#pragma unroll
  for (int i = 0; i < 8; ++i){
    int gr = rowBase + r0 + i;
    if (gr < N){
      unsigned int lo0 = f2bf(acc[i][0]) | (f2bf(acc[i][1]) << 16);
      unsigned int hi0 = f2bf(acc[i][2]) | (f2bf(acc[i][3]) << 16);
      unsigned int lo1 = f2bf(acc[i][4]) | (f2bf(acc[i][5]) << 16);
      unsigned int hi1 = f2bf(acc[i][6]) | (f2bf(acc[i][7]) << 16);
      *(uint2*)(out + (size_t)gr*128 + c0)      = make_uint2(lo0, hi0);
      *(uint2*)(out + (size_t)gr*128 + c0 + 64) = make_uint2(lo1, hi1);
    }
  }
}

// ---------------- alpha_s / alpha_d from bf16 h ----------------
template<int H>
__global__ void alpha_kernel(const unsigned short* __restrict__ hb, const float* __restrict__ a_src,
                             const float* __restrict__ a_dst, float* __restrict__ alpha_s,
                             float* __restrict__ alpha_d, int N){
  int wid = threadIdx.x >> 6, lane = threadIdx.x & 63;
  int n = blockIdx.x * 4 + wid;
  if (n >= N) return;
  unsigned int u = *(const unsigned int*)(hb + (size_t)n*128 + lane*2);
  float hx = bf2f(u & 0xffffu), hy = bf2f(u >> 16);
  float2 as2 = *(const float2*)(a_src + lane*2);
  float2 ad2 = *(const float2*)(a_dst + lane*2);
  float vs = hx*as2.x + hy*as2.y;
  float vd = hx*ad2.x + hy*ad2.y;
  const int L = 64 / H;  // lanes per head
#pragma unroll
  for (int off = 1; off < L; off <<= 1){
    vs += __shfl_xor(vs, off);
    vd += __shfl_xor(vd, off);
  }
  if ((lane % L) == 0){
    int hh = lane / L;
    alpha_s[(size_t)n*H + hh] = vs;
    alpha_d[(size_t)n*H + hh] = vd;
  }
}

// ---------------- single-pass softmax-aggregation (m=0; shift-invariant) ----------------
// wave per node; 4 edges per iteration (16 lanes x bf16x8 each)
template<int H, bool ELU_OUT>
__launch_bounds__(256)
__global__ void agg_kernel(const unsigned short* __restrict__ hb, const float* __restrict__ alpha_s,
                           const float* __restrict__ alpha_d, const int* __restrict__ rowptr,
                           const int* __restrict__ csr_src, const float* __restrict__ bias,
                           float* __restrict__ out, int N){
  int wid = threadIdx.x >> 6, lane = threadIdx.x & 63;
  int n = blockIdx.x * 4 + wid;
  if (n >= N) return;
  int start = rowptr[n];
  int T = rowptr[n + 1] - start + 1;        // +1 self loop (item j==0)

  const int g  = lane >> 4;                 // edge group 0..3
  const int l  = lane & 15;
  const int ch = l * 8;                     // 8 channels per lane
  const int hm = (H == 8) ? (l >> 1) : 0;   // head owning these channels
  const float ad_m = alpha_d[(size_t)n*H + hm];

  float acc[8];
#pragma unroll
  for (int i = 0; i < 8; ++i) acc[i] = 0.f;
  float ssum = 0.f;

  for (int j = g; j < T; j += 4){
    int s = (j == 0) ? n : csr_src[start + j - 1];
    float e  = lrelu(alpha_s[(size_t)s*H + hm] + ad_m);
    float ex = __expf(e);                   // m=0: softmax shift-invariance, |e| small
    int4 hv = *(const int4*)(hb + (size_t)s*128 + ch);
    unsigned int u0 = (unsigned int)hv.x, u1 = (unsigned int)hv.y;
    unsigned int u2 = (unsigned int)hv.z, u3 = (unsigned int)hv.w;
    acc[0] += ex * bf2f(u0 & 0xffffu); acc[1] += ex * bf2f(u0 >> 16);
    acc[2] += ex * bf2f(u1 & 0xffffu); acc[3] += ex * bf2f(u1 >> 16);
    acc[4] += ex * bf2f(u2 & 0xffffu); acc[5] += ex * bf2f(u2 >> 16);
    acc[6] += ex * bf2f(u3 & 0xffffu); acc[7] += ex * bf2f(u3 >> 16);
    ssum += ex;
  }
  // reduce across the 4 edge groups (lanes l, l+16, l+32, l+48)
#pragma unroll
  for (int off = 16; off < 64; off <<= 1){
    ssum += __shfl_xor(ssum, off);
#pragma unroll
    for (int i = 0; i < 8; ++i) acc[i] += __shfl_xor(acc[i], off);
  }

  if (lane < 16){
    float inv = 1.0f / ssum;
    float4 b0 = *(const float4*)(bias + ch);
    float4 b1 = *(const float4*)(bias + ch + 4);
    float o[8] = {acc[0]*inv + b0.x, acc[1]*inv + b0.y, acc[2]*inv + b0.z, acc[3]*inv + b0.w,
                  acc[4]*inv + b1.x, acc[5]*inv + b1.y, acc[6]*inv + b1.z, acc[7]*inv + b1.w};
    if (ELU_OUT){
#pragma unroll
      for (int i = 0; i < 8; ++i) o[i] = (o[i] > 0.f) ? o[i] : expm1f(o[i]);
    }
    *(float4*)(out + (size_t)n*128 + ch)     = make_float4(o[0], o[1], o[2], o[3]);
    *(float4*)(out + (size_t)n*128 + ch + 4) = make_float4(o[4], o[5], o[6], o[7]);
  }
}

extern "C" void kernel_launch(void* const* d_in, const int* in_sizes, int n_in,
                              void* d_out, int out_size, void* d_ws, size_t ws_size,
                              hipStream_t stream){
  const float* x      = (const float*)d_in[0];
  const int*   ei     = (const int*)  d_in[1];
  const float* W1     = (const float*)d_in[2];
  const float* a_src1 = (const float*)d_in[3];
  const float* a_dst1 = (const float*)d_in[4];
  const float* b1     = (const float*)d_in[5];
  const float* W2     = (const float*)d_in[6];
  const float* a_src2 = (const float*)d_in[7];
  const float* a_dst2 = (const float*)d_in[8];
  const float* b2     = (const float*)d_in[9];
  float* out = (float*)d_out;

  const int N = in_sizes[0] / 128;
  const int E = in_sizes[1] / 2;
  const int* src = ei;
  const int* dst = ei + E;

  char* ws = (char*)d_ws;
  size_t off = 0;
  auto alloc = [&](size_t bytes) -> void* {
    void* p = ws + off;
    off += (bytes + 255) & ~(size_t)255;
    return p;
  };
  unsigned short* hb = (unsigned short*)alloc((size_t)N * 128 * 2);  // bf16 h
  float* act    = (float*)alloc((size_t)N * 128 * 4);
  float* asb    = (float*)alloc((size_t)N * 8 * 4);
  float* adb    = (float*)alloc((size_t)N * 8 * 4);
  int*   csr    = (int*)  alloc((size_t)E * 4);
  int*   rowptr = (int*)  alloc((size_t)(N + 1) * 4);
  int*   deg    = (int*)  alloc((size_t)N * 4);
  int*   fill   = (int*)  alloc((size_t)N * 4);
  int*   bsum   = (int*)  alloc(4096);

  hipMemsetAsync(deg, 0, (size_t)((char*)bsum - (char*)deg), stream);

  const int nb = (N + 1023) / 1024;
  hist_kernel   <<<(E + 255)/256, 256, 0, stream>>>(dst, E, deg);
  scan1_kernel  <<<nb, 256, 0, stream>>>(deg, N, rowptr, bsum);
  scan2_kernel  <<<1, 64, 0, stream>>>(bsum, nb);
  scan3_kernel  <<<(N + 255)/256, 256, 0, stream>>>(rowptr, bsum, N);
  scatter_kernel<<<(E + 255)/256, 256, 0, stream>>>(src, dst, E, rowptr, fill, csr);

  const int gBlocks  = (N + 127) / 128;
  const int nBlocks4 = (N + 3) / 4;

  // layer 1
  gemm128_kernel<<<gBlocks, 256, 0, stream>>>(x, W1, hb, N);
  alpha_kernel<8><<<nBlocks4, 256, 0, stream>>>(hb, a_src1, a_dst1, asb, adb, N);
  agg_kernel<8, true><<<nBlocks4, 256, 0, stream>>>(hb, asb, adb, rowptr, csr, b1, act, N);

  // layer 2
  gemm128_kernel<<<gBlocks, 256, 0, stream>>>(act, W2, hb, N);
  alpha_kernel<1><<<nBlocks4, 256, 0, stream>>>(hb, a_src2, a_dst2, asb, adb, N);
  agg_kernel<1, false><<<nBlocks4, 256, 0, stream>>>(hb, asb, adb, rowptr, csr, b2, out, N);
}

// Round 4
// 449.240 us; speedup vs baseline: 1.3683x; 1.0768x over previous
//
#include <hip/hip_runtime.h>
#include <hip/hip_bf16.h>
#include <math.h>

#define NEG_SLOPE 0.2f

__device__ __forceinline__ float lrelu(float x){ return x > 0.0f ? x : NEG_SLOPE * x; }

__device__ __forceinline__ float bf2f(unsigned int u16){
  union { unsigned int i; float f; } v; v.i = u16 << 16; return v.f;
}
__device__ __forceinline__ unsigned int f2bf(float f){
  union { float f; unsigned int i; } v; v.f = f;
  unsigned int x = v.i;
  return (x + 0x7fffu + ((x >> 16) & 1u)) >> 16;   // RNE
}

// ---------------- CSR build (XCD-partitioned by dst range) ----------------
// blocks with blockIdx&7==x handle dst in [x*rangeSize, (x+1)*rangeSize):
// their write window (~800KB csr / ~50KB fill) stays in one XCD's L2, so
// cache lines fill completely before eviction (kills write-allocate blowup).
__global__ void hist_kernel(const int* __restrict__ dst, int E,
                            int* __restrict__ deg, int rangeSize){
  const int x   = blockIdx.x & 7;
  const int gb  = blockIdx.x >> 3;
  const int nGB = gridDim.x >> 3;
  const int lo = x * rangeSize, hi = lo + rangeSize;
  const int stride = nGB * blockDim.x;
  for (int i = gb * blockDim.x + threadIdx.x; i < E; i += stride){
    int d = dst[i];
    if (d >= lo && d < hi) atomicAdd(&deg[d], 1);
  }
}

__global__ void scan1_kernel(const int* __restrict__ deg, int N,
                             int* __restrict__ rowptr, int* __restrict__ bsum){
  __shared__ int sdata[256];
  int t = threadIdx.x;
  int base = blockIdx.x * 1024;
  int v[4];
  int run = 0;
#pragma unroll
  for (int j = 0; j < 4; ++j){
    int idx = base + t*4 + j;
    int d = (idx < N) ? deg[idx] : 0;
    run += d;
    v[j] = run;
  }
  sdata[t] = run;
  __syncthreads();
  for (int off = 1; off < 256; off <<= 1){
    int x = (t >= off) ? sdata[t - off] : 0;
    __syncthreads();
    sdata[t] += x;
    __syncthreads();
  }
  int prev = (t > 0) ? sdata[t-1] : 0;
#pragma unroll
  for (int j = 0; j < 4; ++j){
    int idx = base + t*4 + j;
    if (idx < N) rowptr[idx + 1] = v[j] + prev;
  }
  if (t == 255) bsum[blockIdx.x] = sdata[255];
}

__global__ void scan2_kernel(int* __restrict__ bsum, int nb){
  if (threadIdx.x == 0 && blockIdx.x == 0){
    int run = 0;
    for (int i = 0; i < nb; ++i){ int x = bsum[i]; bsum[i] = run; run += x; }
  }
}

__global__ void scan3_kernel(int* __restrict__ rowptr, const int* __restrict__ bsum, int N){
  int i = blockIdx.x * blockDim.x + threadIdx.x;
  if (i == 0) rowptr[0] = 0;
  if (i < N) rowptr[i + 1] += bsum[i >> 10];
}

__global__ void scatter_kernel(const int* __restrict__ src, const int* __restrict__ dst, int E,
                               const int* __restrict__ rowptr, int* __restrict__ fill,
                               int* __restrict__ csr_src, int rangeSize){
  const int x   = blockIdx.x & 7;
  const int gb  = blockIdx.x >> 3;
  const int nGB = gridDim.x >> 3;
  const int lo = x * rangeSize, hi = lo + rangeSize;
  const int stride = nGB * blockDim.x;
  for (int i = gb * blockDim.x + threadIdx.x; i < E; i += stride){
    int d = dst[i];
    if (d >= lo && d < hi){
      int pos = rowptr[d] + atomicAdd(&fill[d], 1);
      csr_src[pos] = src[i];
    }
  }
}

// ---------------- f32 GEMM -> bf16 out + fused alpha epilogue ----------------
// out[N,128] = A[N,128] @ W[128,128]; also alpha_s/d[n,h] = dot(h[n], a_src/d[h])
template<int H>
__launch_bounds__(256, 4)
__global__ void gemm128_kernel(const float* __restrict__ A, const float* __restrict__ W,
                               unsigned short* __restrict__ out,
                               const float* __restrict__ a_src, const float* __restrict__ a_dst,
                               float* __restrict__ alpha_s, float* __restrict__ alpha_d, int N){
  __shared__ float Wl[32][128];
  __shared__ float xT[32][132];
  const int t = threadIdx.x;
  const int r0 = (t >> 4) * 8;          // 8 rows
  const int c0 = (t & 15) * 4;          // cols c0..c0+3 and c0+64..c0+67
  const int rowBase = blockIdx.x * 128;
  float acc[8][8];
#pragma unroll
  for (int i = 0; i < 8; ++i)
#pragma unroll
    for (int j = 0; j < 8; ++j) acc[i][j] = 0.f;

  for (int kc = 0; kc < 4; ++kc){
#pragma unroll
    for (int j = 0; j < 4; ++j){
      int f = j*256 + t;
      int k = f >> 5, c4 = f & 31;
      *(float4*)(&Wl[k][c4*4]) = *(const float4*)(W + (kc*32 + k)*128 + c4*4);
    }
#pragma unroll
    for (int j = 0; j < 4; ++j){
      int f = j*256 + t;
      int row = f >> 3, kq = f & 7;
      int gr = rowBase + row;
      float4 a = (gr < N) ? *(const float4*)(A + (size_t)gr*128 + kc*32 + kq*4)
                          : make_float4(0.f,0.f,0.f,0.f);
      xT[kq*4 + 0][row] = a.x;
      xT[kq*4 + 1][row] = a.y;
      xT[kq*4 + 2][row] = a.z;
      xT[kq*4 + 3][row] = a.w;
    }
    __syncthreads();
#pragma unroll 4
    for (int k = 0; k < 32; ++k){
      float4 xa = *(const float4*)(&xT[k][r0]);
      float4 xb = *(const float4*)(&xT[k][r0 + 4]);
      float4 wa = *(const float4*)(&Wl[k][c0]);
      float4 wb = *(const float4*)(&Wl[k][c0 + 64]);
      float xr[8] = {xa.x, xa.y, xa.z, xa.w, xb.x, xb.y, xb.z, xb.w};
      float wc[8] = {wa.x, wa.y, wa.z, wa.w, wb.x, wb.y, wb.z, wb.w};
#pragma unroll
      for (int i = 0; i < 8; ++i)
#pragma unroll
        for (int j = 0; j < 8; ++j)
          acc[i][j] += xr[i] * wc[j];
    }
    __syncthreads();
  }

  // bf16 store epilogue
#pragma unroll
  for (int i = 0; i < 8; ++i){
    int gr = rowBase + r0 + i;
    if (gr < N){
      unsigned int lo0 = f2bf(acc[i][0]) | (f2bf(acc[i][1]) << 16);
      unsigned int hi0 = f2bf(acc[i][2]) | (f2bf(acc[i][3]) << 16);
      unsigned int lo1 = f2bf(acc[i][4]) | (f2bf(acc[i][5]) << 16);
      unsigned int hi1 = f2bf(acc[i][6]) | (f2bf(acc[i][7]) << 16);
      *(uint2*)(out + (size_t)gr*128 + c0)      = make_uint2(lo0, hi0);
      *(uint2*)(out + (size_t)gr*128 + c0 + 64) = make_uint2(lo1, hi1);
    }
  }

  // fused alpha epilogue (f32, from acc). a_src/a_dst flat [128]:
  // for H=8, flat index c == h*16 + c_local with h=c/16 — same layout.
  float4 asl = *(const float4*)(a_src + c0);
  float4 ash = *(const float4*)(a_src + c0 + 64);
  float4 adl = *(const float4*)(a_dst + c0);
  float4 adh = *(const float4*)(a_dst + c0 + 64);
#pragma unroll
  for (int i = 0; i < 8; ++i){
    int gr = rowBase + r0 + i;
    float ps_lo = acc[i][0]*asl.x + acc[i][1]*asl.y + acc[i][2]*asl.z + acc[i][3]*asl.w;
    float pd_lo = acc[i][0]*adl.x + acc[i][1]*adl.y + acc[i][2]*adl.z + acc[i][3]*adl.w;
    float ps_hi = acc[i][4]*ash.x + acc[i][5]*ash.y + acc[i][6]*ash.z + acc[i][7]*ash.w;
    float pd_hi = acc[i][4]*adh.x + acc[i][5]*adh.y + acc[i][6]*adh.z + acc[i][7]*adh.w;
    if (H == 8){
      ps_lo += __shfl_xor(ps_lo, 1); ps_lo += __shfl_xor(ps_lo, 2);
      pd_lo += __shfl_xor(pd_lo, 1); pd_lo += __shfl_xor(pd_lo, 2);
      ps_hi += __shfl_xor(ps_hi, 1); ps_hi += __shfl_xor(ps_hi, 2);
      pd_hi += __shfl_xor(pd_hi, 1); pd_hi += __shfl_xor(pd_hi, 2);
      if ((t & 3) == 0 && gr < N){
        int hl = (t & 15) >> 2;
        alpha_s[(size_t)gr*8 + hl]     = ps_lo;
        alpha_s[(size_t)gr*8 + hl + 4] = ps_hi;
        alpha_d[(size_t)gr*8 + hl]     = pd_lo;
        alpha_d[(size_t)gr*8 + hl + 4] = pd_hi;
      }
    } else {
      float ps = ps_lo + ps_hi, pd = pd_lo + pd_hi;
      ps += __shfl_xor(ps, 1); ps += __shfl_xor(ps, 2);
      ps += __shfl_xor(ps, 4); ps += __shfl_xor(ps, 8);
      pd += __shfl_xor(pd, 1); pd += __shfl_xor(pd, 2);
      pd += __shfl_xor(pd, 4); pd += __shfl_xor(pd, 8);
      if ((t & 15) == 0 && gr < N){
        alpha_s[gr] = ps;
        alpha_d[gr] = pd;
      }
    }
  }
}

// ---------------- single-pass softmax-aggregation (m=0; shift-invariant) ----------------
template<int H, bool ELU_OUT>
__launch_bounds__(256)
__global__ void agg_kernel(const unsigned short* __restrict__ hb, const float* __restrict__ alpha_s,
                           const float* __restrict__ alpha_d, const int* __restrict__ rowptr,
                           const int* __restrict__ csr_src, const float* __restrict__ bias,
                           float* __restrict__ out, int N){
  int wid = threadIdx.x >> 6, lane = threadIdx.x & 63;
  int n = blockIdx.x * 4 + wid;
  if (n >= N) return;
  int start = rowptr[n];
  int T = rowptr[n + 1] - start + 1;        // +1 self loop (item j==0)

  const int g  = lane >> 4;                 // edge group 0..3
  const int l  = lane & 15;
  const int ch = l * 8;                     // 8 channels per lane
  const int hm = (H == 8) ? (l >> 1) : 0;   // head owning these channels
  const float ad_m = alpha_d[(size_t)n*H + hm];

  float acc[8];
#pragma unroll
  for (int i = 0; i < 8; ++i) acc[i] = 0.f;
  float ssum = 0.f;

  for (int j = g; j < T; j += 4){
    int s = (j == 0) ? n : csr_src[start + j - 1];
    float e  = lrelu(alpha_s[(size_t)s*H + hm] + ad_m);
    float ex = __expf(e);                   // m=0: softmax shift-invariance, |e| small
    int4 hv = *(const int4*)(hb + (size_t)s*128 + ch);
    unsigned int u0 = (unsigned int)hv.x, u1 = (unsigned int)hv.y;
    unsigned int u2 = (unsigned int)hv.z, u3 = (unsigned int)hv.w;
    acc[0] += ex * bf2f(u0 & 0xffffu); acc[1] += ex * bf2f(u0 >> 16);
    acc[2] += ex * bf2f(u1 & 0xffffu); acc[3] += ex * bf2f(u1 >> 16);
    acc[4] += ex * bf2f(u2 & 0xffffu); acc[5] += ex * bf2f(u2 >> 16);
    acc[6] += ex * bf2f(u3 & 0xffffu); acc[7] += ex * bf2f(u3 >> 16);
    ssum += ex;
  }
#pragma unroll
  for (int off = 16; off < 64; off <<= 1){
    ssum += __shfl_xor(ssum, off);
#pragma unroll
    for (int i = 0; i < 8; ++i) acc[i] += __shfl_xor(acc[i], off);
  }

  if (lane < 16){
    float inv = 1.0f / ssum;
    float4 b0 = *(const float4*)(bias + ch);
    float4 b1 = *(const float4*)(bias + ch + 4);
    float o[8] = {acc[0]*inv + b0.x, acc[1]*inv + b0.y, acc[2]*inv + b0.z, acc[3]*inv + b0.w,
                  acc[4]*inv + b1.x, acc[5]*inv + b1.y, acc[6]*inv + b1.z, acc[7]*inv + b1.w};
    if (ELU_OUT){
#pragma unroll
      for (int i = 0; i < 8; ++i) o[i] = (o[i] > 0.f) ? o[i] : expm1f(o[i]);
    }
    *(float4*)(out + (size_t)n*128 + ch)     = make_float4(o[0], o[1], o[2], o[3]);
    *(float4*)(out + (size_t)n*128 + ch + 4) = make_float4(o[4], o[5], o[6], o[7]);
  }
}

extern "C" void kernel_launch(void* const* d_in, const int* in_sizes, int n_in,
                              void* d_out, int out_size, void* d_ws, size_t ws_size,
                              hipStream_t stream){
  const float* x      = (const float*)d_in[0];
  const int*   ei     = (const int*)  d_in[1];
  const float* W1     = (const float*)d_in[2];
  const float* a_src1 = (const float*)d_in[3];
  const float* a_dst1 = (const float*)d_in[4];
  const float* b1     = (const float*)d_in[5];
  const float* W2     = (const float*)d_in[6];
  const float* a_src2 = (const float*)d_in[7];
  const float* a_dst2 = (const float*)d_in[8];
  const float* b2     = (const float*)d_in[9];
  float* out = (float*)d_out;

  const int N = in_sizes[0] / 128;
  const int E = in_sizes[1] / 2;
  const int* src = ei;
  const int* dst = ei + E;

  char* ws = (char*)d_ws;
  size_t off = 0;
  auto alloc = [&](size_t bytes) -> void* {
    void* p = ws + off;
    off += (bytes + 255) & ~(size_t)255;
    return p;
  };
  unsigned short* hb = (unsigned short*)alloc((size_t)N * 128 * 2);  // bf16 h
  float* act    = (float*)alloc((size_t)N * 128 * 4);
  float* asb    = (float*)alloc((size_t)N * 8 * 4);
  float* adb    = (float*)alloc((size_t)N * 8 * 4);
  int*   csr    = (int*)  alloc((size_t)E * 4);
  int*   rowptr = (int*)  alloc((size_t)(N + 1) * 4);
  int*   deg    = (int*)  alloc((size_t)N * 4);
  int*   fill   = (int*)  alloc((size_t)N * 4);
  int*   bsum   = (int*)  alloc(4096);

  hipMemsetAsync(deg, 0, (size_t)((char*)bsum - (char*)deg), stream);

  const int nb = (N + 1023) / 1024;
  const int rangeSize = (N + 7) / 8;
  hist_kernel   <<<2048, 256, 0, stream>>>(dst, E, deg, rangeSize);
  scan1_kernel  <<<nb, 256, 0, stream>>>(deg, N, rowptr, bsum);
  scan2_kernel  <<<1, 64, 0, stream>>>(bsum, nb);
  scan3_kernel  <<<(N + 255)/256, 256, 0, stream>>>(rowptr, bsum, N);
  scatter_kernel<<<2048, 256, 0, stream>>>(src, dst, E, rowptr, fill, csr, rangeSize);

  const int gBlocks  = (N + 127) / 128;
  const int nBlocks4 = (N + 3) / 4;

  // layer 1
  gemm128_kernel<8><<<gBlocks, 256, 0, stream>>>(x, W1, hb, a_src1, a_dst1, asb, adb, N);
  agg_kernel<8, true><<<nBlocks4, 256, 0, stream>>>(hb, asb, adb, rowptr, csr, b1, act, N);

  // layer 2
  gemm128_kernel<1><<<gBlocks, 256, 0, stream>>>(act, W2, hb, a_src2, a_dst2, asb, adb, N);
  agg_kernel<1, false><<<nBlocks4, 256, 0, stream>>>(hb, asb, adb, rowptr, csr, b2, out, N);
}

// Round 5
// 426.991 us; speedup vs baseline: 1.4396x; 1.0521x over previous
//
#include <hip/hip_runtime.h>
#include <hip/hip_bf16.h>
#include <math.h>

#define NEG_SLOPE 0.2f

typedef _Float16 half8 __attribute__((ext_vector_type(8)));
typedef _Float16 half4 __attribute__((ext_vector_type(4)));
typedef float f32x4 __attribute__((ext_vector_type(4)));

__device__ __forceinline__ float lrelu(float x){ return x > 0.0f ? x : NEG_SLOPE * x; }

// ---------------- CSR build (XCD-partitioned by dst range) ----------------
__global__ void hist_kernel(const int* __restrict__ dst, int E,
                            int* __restrict__ deg, int rangeSize){
  const int x   = blockIdx.x & 7;
  const int gb  = blockIdx.x >> 3;
  const int nGB = gridDim.x >> 3;
  const int lo = x * rangeSize, hi = lo + rangeSize;
  const int stride = nGB * blockDim.x;
  for (int i = gb * blockDim.x + threadIdx.x; i < E; i += stride){
    int d = dst[i];
    if (d >= lo && d < hi) atomicAdd(&deg[d], 1);
  }
}

__global__ void scan1_kernel(const int* __restrict__ deg, int N,
                             int* __restrict__ rowptr, int* __restrict__ bsum){
  __shared__ int sdata[256];
  int t = threadIdx.x;
  int base = blockIdx.x * 1024;
  int v[4];
  int run = 0;
#pragma unroll
  for (int j = 0; j < 4; ++j){
    int idx = base + t*4 + j;
    int d = (idx < N) ? deg[idx] : 0;
    run += d;
    v[j] = run;
  }
  sdata[t] = run;
  __syncthreads();
  for (int off = 1; off < 256; off <<= 1){
    int x = (t >= off) ? sdata[t - off] : 0;
    __syncthreads();
    sdata[t] += x;
    __syncthreads();
  }
  int prev = (t > 0) ? sdata[t-1] : 0;
#pragma unroll
  for (int j = 0; j < 4; ++j){
    int idx = base + t*4 + j;
    if (idx < N) rowptr[idx + 1] = v[j] + prev;
  }
  if (t == 255) bsum[blockIdx.x] = sdata[255];
}

__global__ void scan2_kernel(int* __restrict__ bsum, int nb){
  if (threadIdx.x == 0 && blockIdx.x == 0){
    int run = 0;
    for (int i = 0; i < nb; ++i){ int x = bsum[i]; bsum[i] = run; run += x; }
  }
}

__global__ void scan3_kernel(int* __restrict__ rowptr, const int* __restrict__ bsum, int N){
  int i = blockIdx.x * blockDim.x + threadIdx.x;
  if (i == 0) rowptr[0] = 0;
  if (i < N) rowptr[i + 1] += bsum[i >> 10];
}

__global__ void scatter_kernel(const int* __restrict__ src, const int* __restrict__ dst, int E,
                               const int* __restrict__ rowptr, int* __restrict__ fill,
                               int* __restrict__ csr_src, int rangeSize){
  const int x   = blockIdx.x & 7;
  const int gb  = blockIdx.x >> 3;
  const int nGB = gridDim.x >> 3;
  const int lo = x * rangeSize, hi = lo + rangeSize;
  const int stride = nGB * blockDim.x;
  for (int i = gb * blockDim.x + threadIdx.x; i < E; i += stride){
    int d = dst[i];
    if (d >= lo && d < hi){
      int pos = rowptr[d] + atomicAdd(&fill[d], 1);
      csr_src[pos] = src[i];
    }
  }
}

// ---------------- W prep: cast f32 -> f16, transposed (Wt[col][k] = W[k][col]) ----------------
__global__ void prep_w(const float* __restrict__ W, _Float16* __restrict__ Wt){
  int t = threadIdx.x;
  for (int i = 0; i < 64; ++i){
    int e = i*256 + t;          // 16384 elements
    int k = e >> 7, c = e & 127;
    Wt[c*128 + k] = (_Float16)W[e];
  }
}

// ---------------- MFMA f16 GEMM: h[N,128] = A[N,128] @ W[128,128], fused alpha ----------------
// Swapped operands: D = Wt_frag x X_frag = H^T fragments -> each lane holds 4
// consecutive output COLUMNS (8B f16 stores) for row = lane&15.
template<int H, bool CASTF32>
__launch_bounds__(256, 2)
__global__ void gemm_mfma(const void* __restrict__ Aptr, const _Float16* __restrict__ Wt,
                          _Float16* __restrict__ hout,
                          const float* __restrict__ a_src, const float* __restrict__ a_dst,
                          float* __restrict__ alpha_s, float* __restrict__ alpha_d, int N){
  __shared__ __align__(16) _Float16 Xs[128*128];
  __shared__ __align__(16) _Float16 Ws[128*128];
  __shared__ float apart[2][128][2];
  const int t = threadIdx.x;
  const int lane = t & 63;
  const int w = t >> 6;
  const int wr = w & 1, wc = w >> 1;
  const int rowBase = blockIdx.x * 128;
  const int lrow = lane & 15, lk = lane >> 4;

  // ---- stage X tile (128 rows x 128 k), XOR-swizzled: byte ^= (row&7)<<4
  if (CASTF32){
    const float* A = (const float*)Aptr;
#pragma unroll
    for (int p = 0; p < 16; ++p){
      int flat = p*256 + t;                // 8B LDS chunks
      int row = flat >> 5, seg = flat & 31;
      int gr = rowBase + row;
      float4 v = (gr < N) ? *(const float4*)(A + (size_t)gr*128 + seg*4)
                          : make_float4(0.f,0.f,0.f,0.f);
      half4 hv = {(_Float16)v.x, (_Float16)v.y, (_Float16)v.z, (_Float16)v.w};
      int byt = (row*256 + seg*8) ^ ((row & 7) << 4);
      *(half4*)((char*)Xs + byt) = hv;
    }
  } else {
    const _Float16* A = (const _Float16*)Aptr;
#pragma unroll
    for (int p = 0; p < 8; ++p){
      int flat = p*256 + t;                // 16B chunks
      int row = flat >> 4, seg = flat & 15;
      int gr = rowBase + row;
      int4 v = (gr < N) ? *(const int4*)(A + (size_t)gr*128 + seg*8)
                        : make_int4(0,0,0,0);
      int byt = (row*256 + seg*16) ^ ((row & 7) << 4);
      *(int4*)((char*)Xs + byt) = v;
    }
  }
  // ---- stage Wt (always f16, 128x128)
#pragma unroll
  for (int p = 0; p < 8; ++p){
    int flat = p*256 + t;
    int row = flat >> 4, seg = flat & 15;
    int4 v = *(const int4*)(Wt + row*128 + seg*8);
    int byt = (row*256 + seg*16) ^ ((row & 7) << 4);
    *(int4*)((char*)Ws + byt) = v;
  }
  __syncthreads();

  // ---- K loop: 4 steps of 32
  f32x4 acc[4][4];
#pragma unroll
  for (int mf = 0; mf < 4; ++mf)
#pragma unroll
    for (int nf = 0; nf < 4; ++nf) acc[mf][nf] = (f32x4){0.f,0.f,0.f,0.f};

#pragma unroll
  for (int ks = 0; ks < 4; ++ks){
    const int kbyte = ks*64 + lk*16;
    half8 b[4], a[4];
#pragma unroll
    for (int nf = 0; nf < 4; ++nf){
      int row = wr*64 + nf*16 + lrow;
      b[nf] = *(const half8*)((const char*)Xs + ((row*256 + kbyte) ^ ((row & 7) << 4)));
    }
#pragma unroll
    for (int mf = 0; mf < 4; ++mf){
      int col = wc*64 + mf*16 + lrow;
      a[mf] = *(const half8*)((const char*)Ws + ((col*256 + kbyte) ^ ((col & 7) << 4)));
    }
#pragma unroll
    for (int mf = 0; mf < 4; ++mf)
#pragma unroll
      for (int nf = 0; nf < 4; ++nf)
        acc[mf][nf] = __builtin_amdgcn_mfma_f32_16x16x32_f16(a[mf], b[nf], acc[mf][nf], 0, 0, 0);
  }

  // ---- h store: lane holds rows (nf*16+lrow), cols (wc*64+mf*16+lk*4 .. +3)
#pragma unroll
  for (int nf = 0; nf < 4; ++nf){
    int row = rowBase + wr*64 + nf*16 + lrow;
    if (row < N){
#pragma unroll
      for (int mf = 0; mf < 4; ++mf){
        int col = wc*64 + mf*16 + lk*4;
        f32x4 v = acc[mf][nf];
        half4 hv = {(_Float16)v.x, (_Float16)v.y, (_Float16)v.z, (_Float16)v.w};
        *(half4*)(hout + (size_t)row*128 + col) = hv;
      }
    }
  }

  // ---- fused alpha epilogue (from f32 acc)
  float4 as4[4], ad4[4];
#pragma unroll
  for (int mf = 0; mf < 4; ++mf){
    int cb = wc*64 + mf*16 + lk*4;
    as4[mf] = *(const float4*)(a_src + cb);
    ad4[mf] = *(const float4*)(a_dst + cb);
  }
  if (H == 8){
#pragma unroll
    for (int nf = 0; nf < 4; ++nf){
      int row = rowBase + wr*64 + nf*16 + lrow;
#pragma unroll
      for (int mf = 0; mf < 4; ++mf){
        f32x4 v = acc[mf][nf];
        float ps = v.x*as4[mf].x + v.y*as4[mf].y + v.z*as4[mf].z + v.w*as4[mf].w;
        float pd = v.x*ad4[mf].x + v.y*ad4[mf].y + v.z*ad4[mf].z + v.w*ad4[mf].w;
        ps += __shfl_xor(ps, 16); ps += __shfl_xor(ps, 32);
        pd += __shfl_xor(pd, 16); pd += __shfl_xor(pd, 32);
        if (lane < 16 && row < N){
          int head = wc*4 + mf;
          alpha_s[(size_t)row*8 + head] = ps;
          alpha_d[(size_t)row*8 + head] = pd;
        }
      }
    }
  } else {
#pragma unroll
    for (int nf = 0; nf < 4; ++nf){
      float ps = 0.f, pd = 0.f;
#pragma unroll
      for (int mf = 0; mf < 4; ++mf){
        f32x4 v = acc[mf][nf];
        ps += v.x*as4[mf].x + v.y*as4[mf].y + v.z*as4[mf].z + v.w*as4[mf].w;
        pd += v.x*ad4[mf].x + v.y*ad4[mf].y + v.z*ad4[mf].z + v.w*ad4[mf].w;
      }
      ps += __shfl_xor(ps, 16); ps += __shfl_xor(ps, 32);
      pd += __shfl_xor(pd, 16); pd += __shfl_xor(pd, 32);
      if (lane < 16){
        int rl = wr*64 + nf*16 + lane;
        apart[0][rl][wc] = ps;
        apart[1][rl][wc] = pd;
      }
    }
    __syncthreads();
    if (wc == 0){
      int rl = wr*64 + lane;
      int row = rowBase + rl;
      if (row < N){
        alpha_s[row] = apart[0][rl][0] + apart[0][rl][1];
        alpha_d[row] = apart[1][rl][0] + apart[1][rl][1];
      }
    }
  }
}

// ---------------- per-edge ex precompute for H=1 (kills 16x redundant exp in agg) ----------
__global__ void ex_kernel(const float* __restrict__ as, const float* __restrict__ ad,
                          const int* __restrict__ rowptr, const int* __restrict__ csr,
                          float* __restrict__ ex1, int N){
  int wid = threadIdx.x >> 6, lane = threadIdx.x & 63;
  int n = blockIdx.x * 4 + wid;
  if (n >= N) return;
  int start = rowptr[n], deg = rowptr[n+1] - start;
  float adn = ad[n];
  for (int i = lane; i < deg; i += 64){
    int s = csr[start + i];
    ex1[start + i] = __expf(lrelu(as[s] + adn));
  }
}

// ---------------- single-pass softmax-aggregation (m=0; shift-invariant) ----------------
template<int H>
__launch_bounds__(256)
__global__ void agg_kernel(const _Float16* __restrict__ hb, const float* __restrict__ alpha_s,
                           const float* __restrict__ alpha_d, const float* __restrict__ ex1,
                           const int* __restrict__ rowptr, const int* __restrict__ csr_src,
                           const float* __restrict__ bias, void* __restrict__ outv, int N){
  int wid = threadIdx.x >> 6, lane = threadIdx.x & 63;
  int n = blockIdx.x * 4 + wid;
  if (n >= N) return;
  int start = rowptr[n];
  int T = rowptr[n + 1] - start + 1;        // +1 self loop (item j==0)

  const int g  = lane >> 4;
  const int l  = lane & 15;
  const int ch = l * 8;
  const int hm = (H == 8) ? (l >> 1) : 0;
  float ad_m = 0.f, self_ex = 0.f;
  if (H == 8) ad_m = alpha_d[(size_t)n*8 + hm];
  else        self_ex = __expf(lrelu(alpha_s[n] + alpha_d[n]));

  float acc[8];
#pragma unroll
  for (int i = 0; i < 8; ++i) acc[i] = 0.f;
  float ssum = 0.f;

  for (int j = g; j < T; j += 4){
    int s; float ex;
    if (j == 0){
      s = n;
      ex = (H == 8) ? __expf(lrelu(alpha_s[(size_t)n*8 + hm] + ad_m)) : self_ex;
    } else {
      int p = start + j - 1;
      s = csr_src[p];
      ex = (H == 8) ? __expf(lrelu(alpha_s[(size_t)s*8 + hm] + ad_m)) : ex1[p];
    }
    half8 hv = *(const half8*)(hb + (size_t)s*128 + ch);
#pragma unroll
    for (int i = 0; i < 8; ++i) acc[i] += (float)hv[i] * ex;   // v_fma_mix_f32 target
    ssum += ex;
  }
#pragma unroll
  for (int off = 16; off < 64; off <<= 1){
    ssum += __shfl_xor(ssum, off);
#pragma unroll
    for (int i = 0; i < 8; ++i) acc[i] += __shfl_xor(acc[i], off);
  }

  if (lane < 16){
    float inv = 1.0f / ssum;
    float4 b0 = *(const float4*)(bias + ch);
    float4 b1 = *(const float4*)(bias + ch + 4);
    float o[8] = {acc[0]*inv + b0.x, acc[1]*inv + b0.y, acc[2]*inv + b0.z, acc[3]*inv + b0.w,
                  acc[4]*inv + b1.x, acc[5]*inv + b1.y, acc[6]*inv + b1.z, acc[7]*inv + b1.w};
    if (H == 8){
      // layer-1 output: ELU then f16 (feeds layer-2 MFMA gemm)
      half8 ho;
#pragma unroll
      for (int i = 0; i < 8; ++i){
        float e = (o[i] > 0.f) ? o[i] : expm1f(o[i]);
        ho[i] = (_Float16)e;
      }
      *(half8*)((_Float16*)outv + (size_t)n*128 + ch) = ho;
    } else {
      float* out = (float*)outv;
      *(float4*)(out + (size_t)n*128 + ch)     = make_float4(o[0], o[1], o[2], o[3]);
      *(float4*)(out + (size_t)n*128 + ch + 4) = make_float4(o[4], o[5], o[6], o[7]);
    }
  }
}

extern "C" void kernel_launch(void* const* d_in, const int* in_sizes, int n_in,
                              void* d_out, int out_size, void* d_ws, size_t ws_size,
                              hipStream_t stream){
  const float* x      = (const float*)d_in[0];
  const int*   ei     = (const int*)  d_in[1];
  const float* W1     = (const float*)d_in[2];
  const float* a_src1 = (const float*)d_in[3];
  const float* a_dst1 = (const float*)d_in[4];
  const float* b1     = (const float*)d_in[5];
  const float* W2     = (const float*)d_in[6];
  const float* a_src2 = (const float*)d_in[7];
  const float* a_dst2 = (const float*)d_in[8];
  const float* b2     = (const float*)d_in[9];
  float* out = (float*)d_out;

  const int N = in_sizes[0] / 128;
  const int E = in_sizes[1] / 2;
  const int* src = ei;
  const int* dst = ei + E;

  char* ws = (char*)d_ws;
  size_t off = 0;
  auto alloc = [&](size_t bytes) -> void* {
    void* p = ws + off;
    off += (bytes + 255) & ~(size_t)255;
    return p;
  };
  _Float16* hb   = (_Float16*)alloc((size_t)N * 128 * 2);
  _Float16* act  = (_Float16*)alloc((size_t)N * 128 * 2);
  float* asb     = (float*)alloc((size_t)N * 8 * 4);
  float* adb     = (float*)alloc((size_t)N * 8 * 4);
  float* ex1     = (float*)alloc((size_t)E * 4);
  _Float16* Wt1  = (_Float16*)alloc(16384 * 2);
  _Float16* Wt2  = (_Float16*)alloc(16384 * 2);
  int*   csr     = (int*)  alloc((size_t)E * 4);
  int*   rowptr  = (int*)  alloc((size_t)(N + 1) * 4);
  int*   deg     = (int*)  alloc((size_t)N * 4);
  int*   fill    = (int*)  alloc((size_t)N * 4);
  int*   bsum    = (int*)  alloc(4096);

  hipMemsetAsync(deg, 0, (size_t)((char*)bsum - (char*)deg), stream);

  const int nb = (N + 1023) / 1024;
  const int rangeSize = (N + 7) / 8;
  prep_w        <<<1, 256, 0, stream>>>(W1, Wt1);
  prep_w        <<<1, 256, 0, stream>>>(W2, Wt2);
  hist_kernel   <<<2048, 256, 0, stream>>>(dst, E, deg, rangeSize);
  scan1_kernel  <<<nb, 256, 0, stream>>>(deg, N, rowptr, bsum);
  scan2_kernel  <<<1, 64, 0, stream>>>(bsum, nb);
  scan3_kernel  <<<(N + 255)/256, 256, 0, stream>>>(rowptr, bsum, N);
  scatter_kernel<<<2048, 256, 0, stream>>>(src, dst, E, rowptr, fill, csr, rangeSize);

  const int gBlocks  = (N + 127) / 128;
  const int nBlocks4 = (N + 3) / 4;

  // layer 1: x (f32, cast in staging) @ W1 -> hb f16 + alpha
  gemm_mfma<8, true><<<gBlocks, 256, 0, stream>>>(x, Wt1, hb, a_src1, a_dst1, asb, adb, N);
  agg_kernel<8><<<nBlocks4, 256, 0, stream>>>(hb, asb, adb, nullptr, rowptr, csr, b1, act, N);

  // layer 2: act (f16) @ W2 -> hb f16 + alpha; precompute per-edge ex; aggregate
  gemm_mfma<1, false><<<gBlocks, 256, 0, stream>>>(act, Wt2, hb, a_src2, a_dst2, asb, adb, N);
  ex_kernel<<<nBlocks4, 256, 0, stream>>>(asb, adb, rowptr, csr, ex1, N);
  agg_kernel<1><<<nBlocks4, 256, 0, stream>>>(hb, asb, adb, ex1, rowptr, csr, b2, out, N);
}

// Round 6
// 371.382 us; speedup vs baseline: 1.6552x; 1.1497x over previous
//
#include <hip/hip_runtime.h>
#include <hip/hip_bf16.h>
#include <math.h>

#define NEG_SLOPE 0.2f

typedef _Float16 half8 __attribute__((ext_vector_type(8)));
typedef _Float16 half4 __attribute__((ext_vector_type(4)));
typedef float f32x4 __attribute__((ext_vector_type(4)));

__device__ __forceinline__ float lrelu(float x){ return x > 0.0f ? x : NEG_SLOPE * x; }

// ---------------- CSR build (XCD-partitioned by dst range) ----------------
__global__ void hist_kernel(const int* __restrict__ dst, int E,
                            int* __restrict__ deg, int rangeSize){
  const int x   = blockIdx.x & 7;
  const int gb  = blockIdx.x >> 3;
  const int nGB = gridDim.x >> 3;
  const int lo = x * rangeSize, hi = lo + rangeSize;
  const int stride = nGB * blockDim.x;
  for (int i = gb * blockDim.x + threadIdx.x; i < E; i += stride){
    int d = dst[i];
    if (d >= lo && d < hi) atomicAdd(&deg[d], 1);
  }
}

__global__ void scan1_kernel(const int* __restrict__ deg, int N,
                             int* __restrict__ rowptr, int* __restrict__ bsum){
  __shared__ int sdata[256];
  int t = threadIdx.x;
  int base = blockIdx.x * 1024;
  int v[4];
  int run = 0;
#pragma unroll
  for (int j = 0; j < 4; ++j){
    int idx = base + t*4 + j;
    int d = (idx < N) ? deg[idx] : 0;
    run += d;
    v[j] = run;
  }
  sdata[t] = run;
  __syncthreads();
  for (int off = 1; off < 256; off <<= 1){
    int x = (t >= off) ? sdata[t - off] : 0;
    __syncthreads();
    sdata[t] += x;
    __syncthreads();
  }
  int prev = (t > 0) ? sdata[t-1] : 0;
#pragma unroll
  for (int j = 0; j < 4; ++j){
    int idx = base + t*4 + j;
    if (idx < N) rowptr[idx + 1] = v[j] + prev;
  }
  if (t == 255) bsum[blockIdx.x] = sdata[255];
}

__global__ void scan2_kernel(int* __restrict__ bsum, int nb){
  if (threadIdx.x == 0 && blockIdx.x == 0){
    int run = 0;
    for (int i = 0; i < nb; ++i){ int x = bsum[i]; bsum[i] = run; run += x; }
  }
}

__global__ void scan3_kernel(int* __restrict__ rowptr, const int* __restrict__ bsum, int N){
  int i = blockIdx.x * blockDim.x + threadIdx.x;
  if (i == 0) rowptr[0] = 0;
  if (i < N) rowptr[i + 1] += bsum[i >> 10];
}

__global__ void scatter_kernel(const int* __restrict__ src, const int* __restrict__ dst, int E,
                               const int* __restrict__ rowptr, int* __restrict__ fill,
                               int* __restrict__ csr_src, int rangeSize){
  const int x   = blockIdx.x & 7;
  const int gb  = blockIdx.x >> 3;
  const int nGB = gridDim.x >> 3;
  const int lo = x * rangeSize, hi = lo + rangeSize;
  const int stride = nGB * blockDim.x;
  for (int i = gb * blockDim.x + threadIdx.x; i < E; i += stride){
    int d = dst[i];
    if (d >= lo && d < hi){
      int pos = rowptr[d] + atomicAdd(&fill[d], 1);
      csr_src[pos] = src[i];
    }
  }
}

// ---------------- prep: Wt (f16 transposed) for both layers + w2s/w2d ----------------
__global__ void prep_kernel(const float* __restrict__ W1, const float* __restrict__ W2,
                            const float* __restrict__ as2, const float* __restrict__ ad2,
                            _Float16* __restrict__ Wt1, _Float16* __restrict__ Wt2,
                            float* __restrict__ w2s, float* __restrict__ w2d){
  int t = threadIdx.x;
  if (blockIdx.x < 2){
    const float* W = blockIdx.x ? W2 : W1;
    _Float16* Wt = blockIdx.x ? Wt2 : Wt1;
    for (int i = 0; i < 64; ++i){
      int e = i*256 + t;
      int k = e >> 7, c = e & 127;
      Wt[c*128 + k] = (_Float16)W[e];
    }
  } else {
    // w2s[k] = sum_c W2[k,c] * as2[c]; w2d likewise (128 threads, one k each)
    if (t < 128){
      float ps = 0.f, pd = 0.f;
      for (int c = 0; c < 128; ++c){
        float w = W2[t*128 + c];
        ps += w * as2[c];
        pd += w * ad2[c];
      }
      w2s[t] = ps;
      w2d[t] = pd;
    }
  }
}

// ---------------- MFMA f16 GEMM: h[N,128] = A[N,128] @ W[128,128] ----------------
// Swapped operands: D = Wt_frag x X_frag -> lane holds 4 consecutive output cols.
// ALPHA_H: 8 = per-head alpha epilogue, 1 = single-head alpha, 0 = none.
// OUTF32: f32 output + bias (final gemm); else f16 h output.
template<int ALPHA_H, bool CASTF32, bool OUTF32>
__launch_bounds__(256, 2)
__global__ void gemm_mfma(const void* __restrict__ Aptr, const _Float16* __restrict__ Wt,
                          void* __restrict__ outp, const float* __restrict__ bias,
                          const float* __restrict__ a_src, const float* __restrict__ a_dst,
                          float* __restrict__ alpha_s, float* __restrict__ alpha_d, int N){
  __shared__ __align__(16) _Float16 Xs[128*128];
  __shared__ __align__(16) _Float16 Ws[128*128];
  __shared__ float apart[2][128][2];
  const int t = threadIdx.x;
  const int lane = t & 63;
  const int w = t >> 6;
  const int wr = w & 1, wc = w >> 1;
  const int rowBase = blockIdx.x * 128;
  const int lrow = lane & 15, lk = lane >> 4;

  if (CASTF32){
    const float* A = (const float*)Aptr;
#pragma unroll
    for (int p = 0; p < 16; ++p){
      int flat = p*256 + t;
      int row = flat >> 5, seg = flat & 31;
      int gr = rowBase + row;
      float4 v = (gr < N) ? *(const float4*)(A + (size_t)gr*128 + seg*4)
                          : make_float4(0.f,0.f,0.f,0.f);
      half4 hv = {(_Float16)v.x, (_Float16)v.y, (_Float16)v.z, (_Float16)v.w};
      int byt = (row*256 + seg*8) ^ ((row & 7) << 4);
      *(half4*)((char*)Xs + byt) = hv;
    }
  } else {
    const _Float16* A = (const _Float16*)Aptr;
#pragma unroll
    for (int p = 0; p < 8; ++p){
      int flat = p*256 + t;
      int row = flat >> 4, seg = flat & 15;
      int gr = rowBase + row;
      int4 v = (gr < N) ? *(const int4*)(A + (size_t)gr*128 + seg*8)
                        : make_int4(0,0,0,0);
      int byt = (row*256 + seg*16) ^ ((row & 7) << 4);
      *(int4*)((char*)Xs + byt) = v;
    }
  }
#pragma unroll
  for (int p = 0; p < 8; ++p){
    int flat = p*256 + t;
    int row = flat >> 4, seg = flat & 15;
    int4 v = *(const int4*)(Wt + row*128 + seg*8);
    int byt = (row*256 + seg*16) ^ ((row & 7) << 4);
    *(int4*)((char*)Ws + byt) = v;
  }
  __syncthreads();

  f32x4 acc[4][4];
#pragma unroll
  for (int mf = 0; mf < 4; ++mf)
#pragma unroll
    for (int nf = 0; nf < 4; ++nf) acc[mf][nf] = (f32x4){0.f,0.f,0.f,0.f};

#pragma unroll
  for (int ks = 0; ks < 4; ++ks){
    const int kbyte = ks*64 + lk*16;
    half8 b[4], a[4];
#pragma unroll
    for (int nf = 0; nf < 4; ++nf){
      int row = wr*64 + nf*16 + lrow;
      b[nf] = *(const half8*)((const char*)Xs + ((row*256 + kbyte) ^ ((row & 7) << 4)));
    }
#pragma unroll
    for (int mf = 0; mf < 4; ++mf){
      int col = wc*64 + mf*16 + lrow;
      a[mf] = *(const half8*)((const char*)Ws + ((col*256 + kbyte) ^ ((col & 7) << 4)));
    }
#pragma unroll
    for (int mf = 0; mf < 4; ++mf)
#pragma unroll
      for (int nf = 0; nf < 4; ++nf)
        acc[mf][nf] = __builtin_amdgcn_mfma_f32_16x16x32_f16(a[mf], b[nf], acc[mf][nf], 0, 0, 0);
  }

  if (OUTF32){
    float* outf = (float*)outp;
    float4 b4[4];
#pragma unroll
    for (int mf = 0; mf < 4; ++mf)
      b4[mf] = *(const float4*)(bias + wc*64 + mf*16 + lk*4);
#pragma unroll
    for (int nf = 0; nf < 4; ++nf){
      int row = rowBase + wr*64 + nf*16 + lrow;
      if (row < N){
#pragma unroll
        for (int mf = 0; mf < 4; ++mf){
          int col = wc*64 + mf*16 + lk*4;
          f32x4 v = acc[mf][nf];
          float4 st = make_float4(v.x + b4[mf].x, v.y + b4[mf].y, v.z + b4[mf].z, v.w + b4[mf].w);
          *(float4*)(outf + (size_t)row*128 + col) = st;
        }
      }
    }
  } else {
    _Float16* hout = (_Float16*)outp;
#pragma unroll
    for (int nf = 0; nf < 4; ++nf){
      int row = rowBase + wr*64 + nf*16 + lrow;
      if (row < N){
#pragma unroll
        for (int mf = 0; mf < 4; ++mf){
          int col = wc*64 + mf*16 + lk*4;
          f32x4 v = acc[mf][nf];
          half4 hv = {(_Float16)v.x, (_Float16)v.y, (_Float16)v.z, (_Float16)v.w};
          *(half4*)(hout + (size_t)row*128 + col) = hv;
        }
      }
    }
  }

  if (ALPHA_H > 0){
    float4 as4[4], ad4[4];
#pragma unroll
    for (int mf = 0; mf < 4; ++mf){
      int cb = wc*64 + mf*16 + lk*4;
      as4[mf] = *(const float4*)(a_src + cb);
      ad4[mf] = *(const float4*)(a_dst + cb);
    }
    if (ALPHA_H == 8){
#pragma unroll
      for (int nf = 0; nf < 4; ++nf){
        int row = rowBase + wr*64 + nf*16 + lrow;
#pragma unroll
        for (int mf = 0; mf < 4; ++mf){
          f32x4 v = acc[mf][nf];
          float ps = v.x*as4[mf].x + v.y*as4[mf].y + v.z*as4[mf].z + v.w*as4[mf].w;
          float pd = v.x*ad4[mf].x + v.y*ad4[mf].y + v.z*ad4[mf].z + v.w*ad4[mf].w;
          ps += __shfl_xor(ps, 16); ps += __shfl_xor(ps, 32);
          pd += __shfl_xor(pd, 16); pd += __shfl_xor(pd, 32);
          if (lane < 16 && row < N){
            int head = wc*4 + mf;
            alpha_s[(size_t)row*8 + head] = ps;
            alpha_d[(size_t)row*8 + head] = pd;
          }
        }
      }
    } else {
#pragma unroll
      for (int nf = 0; nf < 4; ++nf){
        float ps = 0.f, pd = 0.f;
#pragma unroll
        for (int mf = 0; mf < 4; ++mf){
          f32x4 v = acc[mf][nf];
          ps += v.x*as4[mf].x + v.y*as4[mf].y + v.z*as4[mf].z + v.w*as4[mf].w;
          pd += v.x*ad4[mf].x + v.y*ad4[mf].y + v.z*ad4[mf].z + v.w*ad4[mf].w;
        }
        ps += __shfl_xor(ps, 16); ps += __shfl_xor(ps, 32);
        pd += __shfl_xor(pd, 16); pd += __shfl_xor(pd, 32);
        if (lane < 16){
          int rl = wr*64 + nf*16 + lane;
          apart[0][rl][wc] = ps;
          apart[1][rl][wc] = pd;
        }
      }
      __syncthreads();
      if (wc == 0){
        int rl = wr*64 + lane;
        int row = rowBase + rl;
        if (row < N){
          alpha_s[row] = apart[0][rl][0] + apart[0][rl][1];
          alpha_d[row] = apart[1][rl][0] + apart[1][rl][1];
        }
      }
    }
  }
}

// ---------------- single-pass softmax-aggregation (m=0; shift-invariant) ----------------
// One wave per node; 4 edge-groups x 16 lanes x 8 channels; inner loop unrolled 2x
// (two independent gather chains in flight). Self-loop peeled to group 3.
// LAYER1: normalize + bias + ELU -> f16 act, plus fused layer-2 alpha epilogue.
// else:   normalize -> f16 agg2 (bias added in final gemm).
template<int H, bool LAYER1>
__launch_bounds__(256)
__global__ void agg_kernel(const _Float16* __restrict__ hb, const float* __restrict__ alpha_s,
                           const float* __restrict__ alpha_d,
                           const int* __restrict__ rowptr, const int* __restrict__ csr_src,
                           const float* __restrict__ bias,
                           const float* __restrict__ w2s, const float* __restrict__ w2d,
                           _Float16* __restrict__ outh,
                           float* __restrict__ as2, float* __restrict__ ad2, int N){
  int wid = threadIdx.x >> 6, lane = threadIdx.x & 63;
  int n = blockIdx.x * 4 + wid;
  if (n >= N) return;
  int start = rowptr[n];
  int deg = rowptr[n + 1] - start;

  const int g  = lane >> 4;
  const int l  = lane & 15;
  const int ch = l * 8;
  const int hm = (H == 8) ? (l >> 1) : 0;
  const float ad_m = alpha_d[(size_t)n*H + hm];

  float acc[8];
#pragma unroll
  for (int i = 0; i < 8; ++i) acc[i] = 0.f;
  float ssum = 0.f;

  // self-loop (group 3)
  if (g == 3){
    float ex = __expf(lrelu(alpha_s[(size_t)n*H + hm] + ad_m));
    half8 hv = *(const half8*)(hb + (size_t)n*128 + ch);
#pragma unroll
    for (int i = 0; i < 8; ++i) acc[i] += (float)hv[i] * ex;
    ssum += ex;
  }

  int i = g;
  for (; i + 4 < deg; i += 8){
    int s0 = csr_src[start + i];
    int s1 = csr_src[start + i + 4];
    float a0 = alpha_s[(size_t)s0*H + hm];
    float a1 = alpha_s[(size_t)s1*H + hm];
    half8 h0 = *(const half8*)(hb + (size_t)s0*128 + ch);
    half8 h1 = *(const half8*)(hb + (size_t)s1*128 + ch);
    float e0 = __expf(lrelu(a0 + ad_m));
    float e1 = __expf(lrelu(a1 + ad_m));
#pragma unroll
    for (int k = 0; k < 8; ++k) acc[k] += (float)h0[k] * e0;
#pragma unroll
    for (int k = 0; k < 8; ++k) acc[k] += (float)h1[k] * e1;
    ssum += e0 + e1;
  }
  if (i < deg){
    int s0 = csr_src[start + i];
    float a0 = alpha_s[(size_t)s0*H + hm];
    half8 h0 = *(const half8*)(hb + (size_t)s0*128 + ch);
    float e0 = __expf(lrelu(a0 + ad_m));
#pragma unroll
    for (int k = 0; k < 8; ++k) acc[k] += (float)h0[k] * e0;
    ssum += e0;
  }

  // reduce across the 4 edge groups
#pragma unroll
  for (int off = 16; off < 64; off <<= 1){
    ssum += __shfl_xor(ssum, off);
#pragma unroll
    for (int k = 0; k < 8; ++k) acc[k] += __shfl_xor(acc[k], off);
  }

  if (lane < 16){
    float inv = 1.0f / ssum;
    float o[8];
    if (LAYER1){
      float4 b0 = *(const float4*)(bias + ch);
      float4 b1 = *(const float4*)(bias + ch + 4);
      float bb[8] = {b0.x,b0.y,b0.z,b0.w,b1.x,b1.y,b1.z,b1.w};
#pragma unroll
      for (int k = 0; k < 8; ++k){
        float v = acc[k]*inv + bb[k];
        o[k] = (v > 0.f) ? v : expm1f(v);       // ELU
      }
    } else {
#pragma unroll
      for (int k = 0; k < 8; ++k) o[k] = acc[k]*inv;
    }
    half8 ho;
#pragma unroll
    for (int k = 0; k < 8; ++k) ho[k] = (_Float16)o[k];
    *(half8*)(outh + (size_t)n*128 + ch) = ho;

    if (LAYER1){
      // fused layer-2 alpha: as2[n] = act[n] . w2s, ad2[n] = act[n] . w2d
      float4 s0 = *(const float4*)(w2s + ch);
      float4 s1 = *(const float4*)(w2s + ch + 4);
      float4 d0 = *(const float4*)(w2d + ch);
      float4 d1 = *(const float4*)(w2d + ch + 4);
      float ps = o[0]*s0.x + o[1]*s0.y + o[2]*s0.z + o[3]*s0.w
               + o[4]*s1.x + o[5]*s1.y + o[6]*s1.z + o[7]*s1.w;
      float pd = o[0]*d0.x + o[1]*d0.y + o[2]*d0.z + o[3]*d0.w
               + o[4]*d1.x + o[5]*d1.y + o[6]*d1.z + o[7]*d1.w;
#pragma unroll
      for (int off = 1; off < 16; off <<= 1){
        ps += __shfl_xor(ps, off);
        pd += __shfl_xor(pd, off);
      }
      if (l == 0){
        as2[n] = ps;
        ad2[n] = pd;
      }
    }
  }
}

extern "C" void kernel_launch(void* const* d_in, const int* in_sizes, int n_in,
                              void* d_out, int out_size, void* d_ws, size_t ws_size,
                              hipStream_t stream){
  const float* x      = (const float*)d_in[0];
  const int*   ei     = (const int*)  d_in[1];
  const float* W1     = (const float*)d_in[2];
  const float* a_src1 = (const float*)d_in[3];
  const float* a_dst1 = (const float*)d_in[4];
  const float* b1     = (const float*)d_in[5];
  const float* W2     = (const float*)d_in[6];
  const float* a_src2 = (const float*)d_in[7];
  const float* a_dst2 = (const float*)d_in[8];
  const float* b2     = (const float*)d_in[9];
  float* out = (float*)d_out;

  const int N = in_sizes[0] / 128;
  const int E = in_sizes[1] / 2;
  const int* src = ei;
  const int* dst = ei + E;

  char* ws = (char*)d_ws;
  size_t off = 0;
  auto alloc = [&](size_t bytes) -> void* {
    void* p = ws + off;
    off += (bytes + 255) & ~(size_t)255;
    return p;
  };
  _Float16* hb   = (_Float16*)alloc((size_t)N * 128 * 2);  // layer-1 h, then reused as agg2
  _Float16* act  = (_Float16*)alloc((size_t)N * 128 * 2);  // layer-1 output (ELU'd)
  float* asb     = (float*)alloc((size_t)N * 8 * 4);
  float* adb     = (float*)alloc((size_t)N * 8 * 4);
  float* as2     = (float*)alloc((size_t)N * 4);
  float* ad2     = (float*)alloc((size_t)N * 4);
  _Float16* Wt1  = (_Float16*)alloc(16384 * 2);
  _Float16* Wt2  = (_Float16*)alloc(16384 * 2);
  float* w2s     = (float*)alloc(128 * 4);
  float* w2d     = (float*)alloc(128 * 4);
  int*   csr     = (int*)  alloc((size_t)E * 4);
  int*   rowptr  = (int*)  alloc((size_t)(N + 1) * 4);
  int*   deg     = (int*)  alloc((size_t)N * 4);
  int*   fill    = (int*)  alloc((size_t)N * 4);
  int*   bsum    = (int*)  alloc(4096);

  hipMemsetAsync(deg, 0, (size_t)((char*)bsum - (char*)deg), stream);

  const int nb = (N + 1023) / 1024;
  const int rangeSize = (N + 7) / 8;
  prep_kernel   <<<3, 256, 0, stream>>>(W1, W2, a_src2, a_dst2, Wt1, Wt2, w2s, w2d);
  hist_kernel   <<<2048, 256, 0, stream>>>(dst, E, deg, rangeSize);
  scan1_kernel  <<<nb, 256, 0, stream>>>(deg, N, rowptr, bsum);
  scan2_kernel  <<<1, 64, 0, stream>>>(bsum, nb);
  scan3_kernel  <<<(N + 255)/256, 256, 0, stream>>>(rowptr, bsum, N);
  scatter_kernel<<<2048, 256, 0, stream>>>(src, dst, E, rowptr, fill, csr, rangeSize);

  const int gBlocks  = (N + 127) / 128;
  const int nBlocks4 = (N + 3) / 4;

  // layer 1: h1 = x@W1 (f16 MFMA) + alpha1 epilogue
  gemm_mfma<8, true, false><<<gBlocks, 256, 0, stream>>>(
      x, Wt1, hb, nullptr, a_src1, a_dst1, asb, adb, N);
  // agg1: act = ELU(P1 . h1 + b1), fused alpha2 = act . (W2^T a2)
  agg_kernel<8, true><<<nBlocks4, 256, 0, stream>>>(
      hb, asb, adb, rowptr, csr, b1, w2s, w2d, act, as2, ad2, N);
  // agg2 = P2 . act (normalized), written into hb (dead)
  agg_kernel<1, false><<<nBlocks4, 256, 0, stream>>>(
      act, as2, ad2, rowptr, csr, nullptr, nullptr, nullptr, hb, nullptr, nullptr, N);
  // out = agg2 @ W2 + b2 (f32 out)
  gemm_mfma<0, false, true><<<gBlocks, 256, 0, stream>>>(
      hb, Wt2, out, b2, nullptr, nullptr, nullptr, nullptr, N);
}